// Round 3
// baseline (895.870 us; speedup 1.0000x reference)
//
#include <hip/hip_runtime.h>

#define H_ 512
#define N_ 32
#define B_ 4
#define L_ 2048
#define LC 128
#define NC 16   // L_/LC

typedef _Float16 f16x8 __attribute__((ext_vector_type(8)));
typedef float f32x4 __attribute__((ext_vector_type(4)));

__device__ inline unsigned short f2h(float f) {
  _Float16 h = (_Float16)f;   // RNE
  return __builtin_bit_cast(unsigned short, h);
}

#define GLD_LDS16(gsrc, ldst)                                                        \
  __builtin_amdgcn_global_load_lds(                                                  \
      (const __attribute__((address_space(1))) unsigned int*)(gsrc),                 \
      (__attribute__((address_space(3))) unsigned int*)(ldst), 16, 0, 0)

// ---------------- precompute Ad, Bd (bilinear), Ad^LC ----------------
__global__ void precompute_k(const float* __restrict__ log_dt,
                             const float* __restrict__ log_A_real,
                             const float* __restrict__ A_imag,
                             const float* __restrict__ B_ri,
                             float4* __restrict__ AB,
                             float2* __restrict__ AP) {
  int i = blockIdx.x * 256 + threadIdx.x;
  if (i >= H_ * N_) return;
  int h = i >> 5;
  int n = i & 31;
  float dt = expf(log_dt[h]);
  float ar = -expf(log_A_real[i]);
  float ai = A_imag[i];
  float dr = 0.5f * dt * ar;
  float di = 0.5f * dt * ai;
  float omr = 1.0f - dr;
  float inv = 1.0f / (omr * omr + di * di);
  float adr = (1.0f - dr * dr - di * di) * inv;
  float adi = 2.0f * di * inv;
  float br = B_ri[2 * n];
  float bi = B_ri[2 * n + 1];
  float bdr = dt * (br * omr - bi * di) * inv;
  float bdi = dt * (br * di + bi * omr) * inv;
  AB[i] = make_float4(adr, adi, bdr, bdi);
  float pr = adr, pi = adi;
#pragma unroll
  for (int s = 0; s < 7; ++s) {  // Ad^(2^7) = Ad^128
    float qr = pr * pr - pi * pi;
    float qi = 2.0f * pr * pi;
    pr = qr; pi = qi;
  }
  AP[i] = make_float2(pr, pi);
}

// ---------------- transpose x (B,L,H) -> xT (B,H,L) ----------------
__global__ void transpose_k(const float* __restrict__ in, float* __restrict__ out) {
  __shared__ float tile[32][33];
  int b = blockIdx.z;
  int t0 = blockIdx.x * 32;
  int h0 = blockIdx.y * 32;
  int tx = threadIdx.x;
  int ty = threadIdx.y;
  const float* src = in + (size_t)b * L_ * H_;
#pragma unroll
  for (int i = 0; i < 32; i += 8)
    tile[ty + i][tx] = src[(size_t)(t0 + ty + i) * H_ + h0 + tx];
  __syncthreads();
  float* dst = out + (size_t)b * H_ * L_;
#pragma unroll
  for (int i = 0; i < 32; i += 8)
    dst[(size_t)(h0 + ty + i) * L_ + t0 + tx] = tile[tx][ty + i];
}

// ---------------- transpose W (K,N) fp32 -> WT (N,K) fp16 ----------------
__global__ void wtrans_k(const float* __restrict__ W1, const float* __restrict__ W2,
                         unsigned short* __restrict__ WT1, unsigned short* __restrict__ WT2) {
  __shared__ float tile[32][33];
  const float* W = blockIdx.z ? W2 : W1;
  unsigned short* WT = blockIdx.z ? WT2 : WT1;
  int k0 = blockIdx.x * 32;
  int j0 = blockIdx.y * 32;
  int tx = threadIdx.x;
  int ty = threadIdx.y;
#pragma unroll
  for (int i = 0; i < 32; i += 8)
    tile[ty + i][tx] = W[(size_t)(k0 + ty + i) * H_ + j0 + tx];
  __syncthreads();
#pragma unroll
  for (int i = 0; i < 32; i += 8)
    WT[(size_t)(j0 + ty + i) * H_ + k0 + tx] = f2h(tile[tx][ty + i]);
}

// ---------------- phase 1: local chunk scans (zero init) ----------------
__global__ __launch_bounds__(256) void phase1_k(const float* __restrict__ xT,
                                                const float4* __restrict__ AB,
                                                float2* __restrict__ xend) {
  int tid = blockIdx.x * 256 + threadIdx.x;
  int n = tid & 31;
  int g = tid >> 5;              // (b*H_ + h)*NC + c
  int c = g & (NC - 1);
  if (c == NC - 1) return;       // last chunk's end-state is never used
  int bh = g >> 4;
  int h = bh & (H_ - 1);
  float4 ab = AB[(h << 5) + n];
  const float4* u4 = (const float4*)(xT + (size_t)bh * L_ + c * LC);
  float xr = 0.f, xi = 0.f;
#pragma unroll 4
  for (int q = 0; q < 32; ++q) {
    float4 uv = u4[q];
#define P1STEP(uu)                                                  \
    {                                                               \
      float nr = fmaf(ab.x, xr, fmaf(-ab.y, xi, ab.z * (uu)));      \
      float ni = fmaf(ab.y, xr, fmaf(ab.x, xi, ab.w * (uu)));       \
      xr = nr; xi = ni;                                             \
    }
    P1STEP(uv.x); P1STEP(uv.y); P1STEP(uv.z); P1STEP(uv.w);
  }
  xend[(size_t)g * 32 + n] = make_float2(xr, xi);
}

// ---------------- phase 2: propagate chunk-boundary states ----------------
__global__ void phase2_k(const float2* __restrict__ xend,
                         const float2* __restrict__ AP,
                         float2* __restrict__ xstart) {
  int tid = blockIdx.x * 256 + threadIdx.x;   // (b*H_+h)*32 + n
  int n = tid & 31;
  int bh = tid >> 5;
  int h = bh & (H_ - 1);
  float2 ap = AP[(h << 5) + n];
  float xr = 0.f, xi = 0.f;
  for (int c = 0; c < NC; ++c) {
    size_t idx = ((size_t)bh * NC + c) * 32 + n;
    xstart[idx] = make_float2(xr, xi);
    if (c < NC - 1) {
      float2 e = xend[idx];
      float nr = fmaf(ap.x, xr, fmaf(-ap.y, xi, e.x));
      float ni = fmaf(ap.y, xr, fmaf(ap.x, xi, e.y));
      xr = nr; xi = ni;
    }
  }
}

// ---------------- phase 3: scan + reduce-scatter butterfly, emit yN fp16 (B,L,H) ----------------
__global__ __launch_bounds__(1024) void phase3_k(const float* __restrict__ xT,
                                                 const float4* __restrict__ AB,
                                                 const float2* __restrict__ Cri,
                                                 const float* __restrict__ Dv,
                                                 const float2* __restrict__ xstart,
                                                 unsigned short* __restrict__ yN) {
  __shared__ float ylds[32][33];
  int tid = threadIdx.x;
  int bid = blockIdx.x;           // c + 16*(ht + 16*b)
  int c = bid & 15;
  int ht = (bid >> 4) & 15;
  int b = bid >> 8;
  int grp = tid >> 5;             // 0..31  -> h = ht*32 + grp
  int n = tid & 31;
  int h = ht * 32 + grp;
  int bh = b * H_ + h;
  float4 ab = AB[(h << 5) + n];
  float2 cc = Cri[(h << 5) + n];
  float dd = Dv[h];
  const float* u = xT + (size_t)bh * L_ + c * LC;
  const float4* u4 = (const float4*)u;
  size_t gidx = ((size_t)bh * NC + c) * 32 + n;
  float2 xs = xstart[gidx];
  float xr = xs.x, xi = xs.y;
  float v[32];
#pragma unroll
  for (int w = 0; w < 4; ++w) {
#pragma unroll
    for (int q = 0; q < 8; ++q) {
      float4 uv = u4[w * 8 + q];
#define P3STEP(uu, idx)                                             \
      {                                                             \
        float nr = fmaf(ab.x, xr, fmaf(-ab.y, xi, ab.z * (uu)));    \
        float ni = fmaf(ab.y, xr, fmaf(ab.x, xi, ab.w * (uu)));     \
        xr = nr; xi = ni;                                           \
        v[(idx)] = fmaf(cc.x, xr, -(cc.y * xi));                    \
      }
      P3STEP(uv.x, q * 4 + 0);
      P3STEP(uv.y, q * 4 + 1);
      P3STEP(uv.z, q * 4 + 2);
      P3STEP(uv.w, q * 4 + 3);
    }
    // reduce-scatter butterfly: after this, v[0] = sum_n p_n[t = w*32 + n_lane]
#pragma unroll
    for (int m = 16; m >= 1; m >>= 1) {
#pragma unroll
      for (int j = 0; j < m; ++j) {
        bool hi = (n & m) != 0;
        float snd = hi ? v[j] : v[j + m];
        float rcv = __shfl_xor(snd, m);
        float kp = hi ? v[j + m] : v[j];
        v[j] = kp + rcv;
      }
    }
    float ul = u[w * 32 + n];
    float f = fmaf(dd, ul, v[0]);   // y[t = w*32 + n] for this h
    ylds[n][grp] = f;
    __syncthreads();
    // write 32t x 32h tile, h contiguous
    int t = tid >> 5;
    int hh = tid & 31;
    float val = ylds[t][hh];
    yN[((size_t)b * L_ + c * LC + w * 32 + t) * H_ + ht * 32 + hh] = f2h(val);
    __syncthreads();
  }
}

// ---------------- fused GLU GEMM (fp16 MFMA): out = (y@W1) * sigmoid(y@W2) ----------------
// A = yN (M=8192, K=512) fp16 row-major; B = WT1/WT2 (N=512, K=512) fp16 row-major.
// BM=128, BN=64, BK=64; 4 waves, wave tile 64x32.
__global__ __launch_bounds__(256) void glu_gemm_k(const unsigned short* __restrict__ yN,
                                                  const unsigned short* __restrict__ WT1,
                                                  const unsigned short* __restrict__ WT2,
                                                  float* __restrict__ out) {
  __shared__ __align__(16) char lds[49152];   // A:16KB  B1:8KB  B2:8KB (+slack)
  char* As = lds;
  char* B1s = lds + 16384;
  char* B2s = lds + 24576;
  int tid = threadIdx.x;
  int m0 = blockIdx.x * 128;
  int n0 = blockIdx.y * 64;
  int wave = tid >> 6;
  int lane = tid & 63;
  int wm = wave >> 1;
  int wn = wave & 1;
  int srow = tid >> 3;          // 0..31
  int scb = (tid & 7) * 16;     // col-bytes within 128B row

  f32x4 acc1[4][2], acc2[4][2];
#pragma unroll
  for (int mf = 0; mf < 4; ++mf)
#pragma unroll
    for (int nf = 0; nf < 2; ++nf) {
      f32x4 z; z[0] = 0.f; z[1] = 0.f; z[2] = 0.f; z[3] = 0.f;
      acc1[mf][nf] = z; acc2[mf][nf] = z;
    }

  const char* ybase = (const char*)yN;
  const char* b1base = (const char*)WT1;
  const char* b2base = (const char*)WT2;

  for (int k0 = 0; k0 < H_; k0 += 64) {
    // stage A tile [128 m][64 k], linear LDS dest, pre-swizzled global source
#pragma unroll
    for (int i = 0; i < 4; ++i) {
      int row = i * 32 + srow;
      int sc = scb ^ ((row & 7) << 4);
      const char* src = ybase + ((size_t)(m0 + row) * H_ + k0) * 2 + sc;
      GLD_LDS16(src, As + wave * 1024 + i * 4096);
    }
    // stage B tiles [64 n][64 k]
#pragma unroll
    for (int i = 0; i < 2; ++i) {
      int row = i * 32 + srow;
      int sc = scb ^ ((row & 7) << 4);
      const char* s1 = b1base + ((size_t)(n0 + row) * H_ + k0) * 2 + sc;
      const char* s2 = b2base + ((size_t)(n0 + row) * H_ + k0) * 2 + sc;
      GLD_LDS16(s1, B1s + wave * 1024 + i * 4096);
      GLD_LDS16(s2, B2s + wave * 1024 + i * 4096);
    }
    __syncthreads();
#pragma unroll
    for (int ks = 0; ks < 2; ++ks) {
      f16x8 a[4], b1[2], b2[2];
      int kb = ks * 64 + (lane >> 4) * 16;
#pragma unroll
      for (int mf = 0; mf < 4; ++mf) {
        int row = wm * 64 + mf * 16 + (lane & 15);
        a[mf] = *(const f16x8*)(As + row * 128 + (kb ^ ((row & 7) << 4)));
      }
#pragma unroll
      for (int nf = 0; nf < 2; ++nf) {
        int row = wn * 32 + nf * 16 + (lane & 15);
        int off = row * 128 + (kb ^ ((row & 7) << 4));
        b1[nf] = *(const f16x8*)(B1s + off);
        b2[nf] = *(const f16x8*)(B2s + off);
      }
#pragma unroll
      for (int mf = 0; mf < 4; ++mf)
#pragma unroll
        for (int nf = 0; nf < 2; ++nf) {
          acc1[mf][nf] = __builtin_amdgcn_mfma_f32_16x16x32_f16(a[mf], b1[nf], acc1[mf][nf], 0, 0, 0);
          acc2[mf][nf] = __builtin_amdgcn_mfma_f32_16x16x32_f16(a[mf], b2[nf], acc2[mf][nf], 0, 0, 0);
        }
    }
    __syncthreads();
  }
  // epilogue: o = g1 * sigmoid(g2); D layout col=lane&15, row=(lane>>4)*4+r
  int nb = n0 + wn * 32 + (lane & 15);
  int rbase = (lane >> 4) * 4;
#pragma unroll
  for (int mf = 0; mf < 4; ++mf)
#pragma unroll
    for (int nf = 0; nf < 2; ++nf)
#pragma unroll
      for (int r = 0; r < 4; ++r) {
        int m = m0 + wm * 64 + mf * 16 + rbase + r;
        float g1 = acc1[mf][nf][r];
        float g2 = acc2[mf][nf][r];
        out[(size_t)m * H_ + nb + nf * 16] = g1 / (1.0f + __expf(-g2));
      }
}

extern "C" void kernel_launch(void* const* d_in, const int* in_sizes, int n_in,
                              void* d_out, int out_size, void* d_ws, size_t ws_size,
                              hipStream_t stream) {
  (void)in_sizes; (void)n_in; (void)out_size; (void)ws_size;
  const float* x          = (const float*)d_in[0];
  const float* log_dt     = (const float*)d_in[1];
  const float* log_A_real = (const float*)d_in[2];
  const float* A_imag     = (const float*)d_in[3];
  const float* B_ri       = (const float*)d_in[4];
  const float* C_ri       = (const float*)d_in[5];
  const float* Dv         = (const float*)d_in[6];
  const float* W1         = (const float*)d_in[7];
  const float* W2         = (const float*)d_in[8];
  float* out = (float*)d_out;
  char* ws = (char*)d_ws;

  float*          xT     = (float*)(ws);                                // 16 MiB
  unsigned short* yN     = (unsigned short*)(ws + (16u << 20));         // 8 MiB
  float4*         AB     = (float4*)(ws + (24u << 20));                 // 256 KiB
  float2*         AP     = (float2*)(ws + (24u << 20) + (256u << 10));  // 128 KiB
  float2*         xend   = (float2*)(ws + (25u << 20));                 // 8 MiB
  float2*         xstart = (float2*)(ws + (33u << 20));                 // 8 MiB
  unsigned short* WT1    = (unsigned short*)(ws + (41u << 20));         // 512 KiB
  unsigned short* WT2    = (unsigned short*)(ws + (41u << 20) + (512u << 10));

  precompute_k<<<(H_ * N_ + 255) / 256, 256, 0, stream>>>(log_dt, log_A_real, A_imag, B_ri, AB, AP);

  dim3 tgrid(L_ / 32, H_ / 32, B_);
  dim3 tblock(32, 8);
  transpose_k<<<tgrid, tblock, 0, stream>>>(x, xT);

  dim3 wgrid(H_ / 32, H_ / 32, 2);
  wtrans_k<<<wgrid, tblock, 0, stream>>>(W1, W2, WT1, WT2);

  phase1_k<<<(B_ * H_ * NC * 32) / 256, 256, 0, stream>>>(xT, AB, xend);
  phase2_k<<<(B_ * H_ * N_) / 256, 256, 0, stream>>>(xend, AP, xstart);
  phase3_k<<<B_ * (H_ / 32) * NC, 1024, 0, stream>>>(xT, AB, (const float2*)C_ri, Dv, xstart, yN);

  dim3 ggrid((B_ * L_) / 128, H_ / 64);
  glu_gemm_k<<<ggrid, 256, 0, stream>>>(yN, WT1, WT2, out);
}

// Round 4
// 94.571 us; speedup vs baseline: 9.4730x; 9.4730x over previous
//
#include <hip/hip_runtime.h>

#define H_ 512
#define N_ 32
#define B_ 4
#define L_ 2048
#define LC 128
#define NC 16   // L_/LC

typedef _Float16 f16x8 __attribute__((ext_vector_type(8)));
typedef float f32x4 __attribute__((ext_vector_type(4)));

__device__ inline unsigned short f2h(float f) {
  _Float16 h = (_Float16)f;   // RNE
  return __builtin_bit_cast(unsigned short, h);
}

#define GLD_LDS16(gsrc, ldst)                                                        \
  __builtin_amdgcn_global_load_lds(                                                  \
      (const __attribute__((address_space(1))) unsigned int*)(gsrc),                 \
      (__attribute__((address_space(3))) unsigned int*)(ldst), 16, 0, 0)

// ---------------- precompute Ad, Bd (bilinear), Ad^LC ----------------
__global__ void precompute_k(const float* __restrict__ log_dt,
                             const float* __restrict__ log_A_real,
                             const float* __restrict__ A_imag,
                             const float* __restrict__ B_ri,
                             float4* __restrict__ AB,
                             float2* __restrict__ AP) {
  int i = blockIdx.x * 256 + threadIdx.x;
  if (i >= H_ * N_) return;
  int h = i >> 5;
  int n = i & 31;
  float dt = expf(log_dt[h]);
  float ar = -expf(log_A_real[i]);
  float ai = A_imag[i];
  float dr = 0.5f * dt * ar;
  float di = 0.5f * dt * ai;
  float omr = 1.0f - dr;
  float inv = 1.0f / (omr * omr + di * di);
  float adr = (1.0f - dr * dr - di * di) * inv;
  float adi = 2.0f * di * inv;
  float br = B_ri[2 * n];
  float bi = B_ri[2 * n + 1];
  float bdr = dt * (br * omr - bi * di) * inv;
  float bdi = dt * (br * di + bi * omr) * inv;
  AB[i] = make_float4(adr, adi, bdr, bdi);
  float pr = adr, pi = adi;
#pragma unroll
  for (int s = 0; s < 7; ++s) {  // Ad^(2^7) = Ad^128
    float qr = pr * pr - pi * pi;
    float qi = 2.0f * pr * pi;
    pr = qr; pi = qi;
  }
  AP[i] = make_float2(pr, pi);
}

// ---------------- transpose x (B,L,H) -> xT (B,H,L) ----------------
__global__ void transpose_k(const float* __restrict__ in, float* __restrict__ out) {
  __shared__ float tile[32][33];
  int b = blockIdx.z;
  int t0 = blockIdx.x * 32;
  int h0 = blockIdx.y * 32;
  int tx = threadIdx.x;
  int ty = threadIdx.y;
  const float* src = in + (size_t)b * L_ * H_;
#pragma unroll
  for (int i = 0; i < 32; i += 8)
    tile[ty + i][tx] = src[(size_t)(t0 + ty + i) * H_ + h0 + tx];
  __syncthreads();
  float* dst = out + (size_t)b * H_ * L_;
#pragma unroll
  for (int i = 0; i < 32; i += 8)
    dst[(size_t)(h0 + ty + i) * L_ + t0 + tx] = tile[tx][ty + i];
}

// ---------------- transpose W (K,N) fp32 -> WT (N,K) fp16 ----------------
__global__ void wtrans_k(const float* __restrict__ W1, const float* __restrict__ W2,
                         unsigned short* __restrict__ WT1, unsigned short* __restrict__ WT2) {
  __shared__ float tile[32][33];
  const float* W = blockIdx.z ? W2 : W1;
  unsigned short* WT = blockIdx.z ? WT2 : WT1;
  int k0 = blockIdx.x * 32;
  int j0 = blockIdx.y * 32;
  int tx = threadIdx.x;
  int ty = threadIdx.y;
#pragma unroll
  for (int i = 0; i < 32; i += 8)
    tile[ty + i][tx] = W[(size_t)(k0 + ty + i) * H_ + j0 + tx];
  __syncthreads();
#pragma unroll
  for (int i = 0; i < 32; i += 8)
    WT[(size_t)(j0 + ty + i) * H_ + k0 + tx] = f2h(tile[tx][ty + i]);
}

// ---------------- phase 1: local chunk scans (zero init) ----------------
__global__ __launch_bounds__(256) void phase1_k(const float* __restrict__ xT,
                                                const float4* __restrict__ AB,
                                                float2* __restrict__ xend) {
  int tid = blockIdx.x * 256 + threadIdx.x;
  int n = tid & 31;
  int g = tid >> 5;              // (b*H_ + h)*NC + c
  int c = g & (NC - 1);
  if (c == NC - 1) return;       // last chunk's end-state is never used
  int bh = g >> 4;
  int h = bh & (H_ - 1);
  float4 ab = AB[(h << 5) + n];
  const float4* u4 = (const float4*)(xT + (size_t)bh * L_ + c * LC);
  float xr = 0.f, xi = 0.f;
#pragma unroll 4
  for (int q = 0; q < 32; ++q) {
    float4 uv = u4[q];
#define P1STEP(uu)                                                  \
    {                                                               \
      float nr = fmaf(ab.x, xr, fmaf(-ab.y, xi, ab.z * (uu)));      \
      float ni = fmaf(ab.y, xr, fmaf(ab.x, xi, ab.w * (uu)));       \
      xr = nr; xi = ni;                                             \
    }
    P1STEP(uv.x); P1STEP(uv.y); P1STEP(uv.z); P1STEP(uv.w);
  }
  xend[(size_t)g * 32 + n] = make_float2(xr, xi);
}

// ---------------- phase 2: propagate chunk-boundary states ----------------
__global__ void phase2_k(const float2* __restrict__ xend,
                         const float2* __restrict__ AP,
                         float2* __restrict__ xstart) {
  int tid = blockIdx.x * 256 + threadIdx.x;   // (b*H_+h)*32 + n
  int n = tid & 31;
  int bh = tid >> 5;
  int h = bh & (H_ - 1);
  float2 ap = AP[(h << 5) + n];
  float xr = 0.f, xi = 0.f;
  for (int c = 0; c < NC; ++c) {
    size_t idx = ((size_t)bh * NC + c) * 32 + n;
    xstart[idx] = make_float2(xr, xi);
    if (c < NC - 1) {
      float2 e = xend[idx];
      float nr = fmaf(ap.x, xr, fmaf(-ap.y, xi, e.x));
      float ni = fmaf(ap.y, xr, fmaf(ap.x, xi, e.y));
      xr = nr; xi = ni;
    }
  }
}

// ---------------- phase 3: 8-lane groups, 4 n per lane, v[8] butterfly ----------------
// group (8 lanes) <-> one (b,h,c). lane owns n = ln*4 .. ln*4+3.
// Per 8-step window: v[s] accumulates (D/8)*u_s + sum_{own n} Re(C*x); 3-stage
// butterfly (literal indices only) reduce-scatters so lane ln holds y[t0+ln].
__global__ __launch_bounds__(256) void phase3_k(const float* __restrict__ xT,
                                                const float4* __restrict__ AB,
                                                const float2* __restrict__ Cri,
                                                const float* __restrict__ Dv,
                                                const float2* __restrict__ xstart,
                                                unsigned short* __restrict__ yN) {
  __shared__ float ylds[8][36];
  int tid = threadIdx.x;
  int bid = blockIdx.x;           // c + 16*(ht + 16*b)
  int c = bid & 15;
  int ht = (bid >> 4) & 15;
  int b = bid >> 8;
  int grp = tid >> 3;             // 0..31 -> h = ht*32 + grp
  int ln = tid & 7;               // 0..7
  int h = ht * 32 + grp;
  int bh = b * H_ + h;

  float4 ab[4];
  float2 cc[4];
#pragma unroll
  for (int i = 0; i < 4; ++i) {
    ab[i] = AB[(h << 5) + ln * 4 + i];
    cc[i] = Cri[(h << 5) + ln * 4 + i];
  }
  float dd8 = Dv[h] * 0.125f;

  const float4* u4 = (const float4*)(xT + (size_t)bh * L_ + c * LC);
  const float4* xs4 = (const float4*)(xstart + ((size_t)(bh * NC + c) * 32 + ln * 4));
  float4 s01 = xs4[0], s23 = xs4[1];
  float xr[4] = {s01.x, s01.z, s23.x, s23.z};
  float xi[4] = {s01.y, s01.w, s23.y, s23.w};

  float4 uv0 = u4[0], uv1 = u4[1];
#pragma unroll
  for (int w = 0; w < 16; ++w) {
    float4 nv0, nv1;
    if (w < 15) { nv0 = u4[w * 2 + 2]; nv1 = u4[w * 2 + 3]; }
    float v[8];
#define P3STEP(S, UU)                                                        \
    {                                                                        \
      float uu = (UU);                                                       \
      float acc = dd8 * uu;                                                  \
      _Pragma("unroll")                                                      \
      for (int i = 0; i < 4; ++i) {                                          \
        float nr = fmaf(ab[i].x, xr[i], fmaf(-ab[i].y, xi[i], ab[i].z * uu));\
        float ni = fmaf(ab[i].y, xr[i], fmaf(ab[i].x, xi[i], ab[i].w * uu));\
        xr[i] = nr; xi[i] = ni;                                              \
        acc = fmaf(cc[i].x, nr, fmaf(-cc[i].y, ni, acc));                    \
      }                                                                      \
      v[(S)] = acc;                                                          \
    }
    P3STEP(0, uv0.x); P3STEP(1, uv0.y); P3STEP(2, uv0.z); P3STEP(3, uv0.w);
    P3STEP(4, uv1.x); P3STEP(5, uv1.y); P3STEP(6, uv1.z); P3STEP(7, uv1.w);
    // 3-stage reduce-scatter butterfly over 8 lanes; all indices literal.
#define BFLY(J, M)                                                           \
    {                                                                        \
      bool hi = (ln & (M)) != 0;                                             \
      float snd = hi ? v[(J)] : v[(J) + (M)];                                \
      float rcv = __shfl_xor(snd, (M));                                      \
      float kp = hi ? v[(J) + (M)] : v[(J)];                                 \
      v[(J)] = kp + rcv;                                                     \
    }
    BFLY(0, 4) BFLY(1, 4) BFLY(2, 4) BFLY(3, 4)
    BFLY(0, 2) BFLY(1, 2)
    BFLY(0, 1)
    // lane ln now holds y[t0+ln] for this h
    ylds[ln][grp] = v[0];
    __syncthreads();
    int t = tid >> 5;           // 0..7
    int hh = tid & 31;
    float val = ylds[t][hh];
    yN[((size_t)b * L_ + c * LC + w * 8 + t) * H_ + ht * 32 + hh] = f2h(val);
    __syncthreads();
    uv0 = nv0; uv1 = nv1;
  }
}

// ---------------- fused GLU GEMM (fp16 MFMA): out = (y@W1) * sigmoid(y@W2) ----------------
// A = yN (M=8192, K=512) fp16 row-major; B = WT1/WT2 (N=512, K=512) fp16 row-major.
// BM=128, BN=64, BK=64; 4 waves, wave tile 64x32.
__global__ __launch_bounds__(256) void glu_gemm_k(const unsigned short* __restrict__ yN,
                                                  const unsigned short* __restrict__ WT1,
                                                  const unsigned short* __restrict__ WT2,
                                                  float* __restrict__ out) {
  __shared__ __align__(16) char lds[49152];   // A:16KB  B1:8KB  B2:8KB (+slack)
  char* As = lds;
  char* B1s = lds + 16384;
  char* B2s = lds + 24576;
  int tid = threadIdx.x;
  int m0 = blockIdx.x * 128;
  int n0 = blockIdx.y * 64;
  int wave = tid >> 6;
  int lane = tid & 63;
  int wm = wave >> 1;
  int wn = wave & 1;
  int srow = tid >> 3;          // 0..31
  int scb = (tid & 7) * 16;     // col-bytes within 128B row

  f32x4 acc1[4][2], acc2[4][2];
#pragma unroll
  for (int mf = 0; mf < 4; ++mf)
#pragma unroll
    for (int nf = 0; nf < 2; ++nf) {
      f32x4 z; z[0] = 0.f; z[1] = 0.f; z[2] = 0.f; z[3] = 0.f;
      acc1[mf][nf] = z; acc2[mf][nf] = z;
    }

  const char* ybase = (const char*)yN;
  const char* b1base = (const char*)WT1;
  const char* b2base = (const char*)WT2;

  for (int k0 = 0; k0 < H_; k0 += 64) {
    // stage A tile [128 m][64 k], linear LDS dest, pre-swizzled global source
#pragma unroll
    for (int i = 0; i < 4; ++i) {
      int row = i * 32 + srow;
      int sc = scb ^ ((row & 7) << 4);
      const char* src = ybase + ((size_t)(m0 + row) * H_ + k0) * 2 + sc;
      GLD_LDS16(src, As + wave * 1024 + i * 4096);
    }
    // stage B tiles [64 n][64 k]
#pragma unroll
    for (int i = 0; i < 2; ++i) {
      int row = i * 32 + srow;
      int sc = scb ^ ((row & 7) << 4);
      const char* s1 = b1base + ((size_t)(n0 + row) * H_ + k0) * 2 + sc;
      const char* s2 = b2base + ((size_t)(n0 + row) * H_ + k0) * 2 + sc;
      GLD_LDS16(s1, B1s + wave * 1024 + i * 4096);
      GLD_LDS16(s2, B2s + wave * 1024 + i * 4096);
    }
    __syncthreads();
#pragma unroll
    for (int ks = 0; ks < 2; ++ks) {
      f16x8 a[4], b1[2], b2[2];
      int kb = ks * 64 + (lane >> 4) * 16;
#pragma unroll
      for (int mf = 0; mf < 4; ++mf) {
        int row = wm * 64 + mf * 16 + (lane & 15);
        a[mf] = *(const f16x8*)(As + row * 128 + (kb ^ ((row & 7) << 4)));
      }
#pragma unroll
      for (int nf = 0; nf < 2; ++nf) {
        int row = wn * 32 + nf * 16 + (lane & 15);
        int off = row * 128 + (kb ^ ((row & 7) << 4));
        b1[nf] = *(const f16x8*)(B1s + off);
        b2[nf] = *(const f16x8*)(B2s + off);
      }
#pragma unroll
      for (int mf = 0; mf < 4; ++mf)
#pragma unroll
        for (int nf = 0; nf < 2; ++nf) {
          acc1[mf][nf] = __builtin_amdgcn_mfma_f32_16x16x32_f16(a[mf], b1[nf], acc1[mf][nf], 0, 0, 0);
          acc2[mf][nf] = __builtin_amdgcn_mfma_f32_16x16x32_f16(a[mf], b2[nf], acc2[mf][nf], 0, 0, 0);
        }
    }
    __syncthreads();
  }
  // epilogue: o = g1 * sigmoid(g2); D layout col=lane&15, row=(lane>>4)*4+r
  int nb = n0 + wn * 32 + (lane & 15);
  int rbase = (lane >> 4) * 4;
#pragma unroll
  for (int mf = 0; mf < 4; ++mf)
#pragma unroll
    for (int nf = 0; nf < 2; ++nf)
#pragma unroll
      for (int r = 0; r < 4; ++r) {
        int m = m0 + wm * 64 + mf * 16 + rbase + r;
        float g1 = acc1[mf][nf][r];
        float g2 = acc2[mf][nf][r];
        out[(size_t)m * H_ + nb + nf * 16] = g1 / (1.0f + __expf(-g2));
      }
}

extern "C" void kernel_launch(void* const* d_in, const int* in_sizes, int n_in,
                              void* d_out, int out_size, void* d_ws, size_t ws_size,
                              hipStream_t stream) {
  (void)in_sizes; (void)n_in; (void)out_size; (void)ws_size;
  const float* x          = (const float*)d_in[0];
  const float* log_dt     = (const float*)d_in[1];
  const float* log_A_real = (const float*)d_in[2];
  const float* A_imag     = (const float*)d_in[3];
  const float* B_ri       = (const float*)d_in[4];
  const float* C_ri       = (const float*)d_in[5];
  const float* Dv         = (const float*)d_in[6];
  const float* W1         = (const float*)d_in[7];
  const float* W2         = (const float*)d_in[8];
  float* out = (float*)d_out;
  char* ws = (char*)d_ws;

  float*          xT     = (float*)(ws);                                // 16 MiB
  unsigned short* yN     = (unsigned short*)(ws + (16u << 20));         // 8 MiB
  float4*         AB     = (float4*)(ws + (24u << 20));                 // 256 KiB
  float2*         AP     = (float2*)(ws + (24u << 20) + (256u << 10));  // 128 KiB
  float2*         xend   = (float2*)(ws + (25u << 20));                 // 8 MiB
  float2*         xstart = (float2*)(ws + (33u << 20));                 // 8 MiB
  unsigned short* WT1    = (unsigned short*)(ws + (41u << 20));         // 512 KiB
  unsigned short* WT2    = (unsigned short*)(ws + (41u << 20) + (512u << 10));

  precompute_k<<<(H_ * N_ + 255) / 256, 256, 0, stream>>>(log_dt, log_A_real, A_imag, B_ri, AB, AP);

  dim3 tgrid(L_ / 32, H_ / 32, B_);
  dim3 tblock(32, 8);
  transpose_k<<<tgrid, tblock, 0, stream>>>(x, xT);

  dim3 wgrid(H_ / 32, H_ / 32, 2);
  wtrans_k<<<wgrid, tblock, 0, stream>>>(W1, W2, WT1, WT2);

  phase1_k<<<(B_ * H_ * NC * 32) / 256, 256, 0, stream>>>(xT, AB, xend);
  phase2_k<<<(B_ * H_ * N_) / 256, 256, 0, stream>>>(xend, AP, xstart);
  phase3_k<<<B_ * (H_ / 32) * NC, 256, 0, stream>>>(xT, AB, (const float2*)C_ri, Dv, xstart, yN);

  dim3 ggrid((B_ * L_) / 128, H_ / 64);
  glu_gemm_k<<<ggrid, 256, 0, stream>>>(yN, WT1, WT2, out);
}

// Round 5
// 80.270 us; speedup vs baseline: 11.1608x; 1.1782x over previous
//
#include <hip/hip_runtime.h>

#define H_ 512
#define N_ 32
#define B_ 4
#define L_ 2048
#define LC 128
#define NC 16   // L_/LC

typedef _Float16 f16x8 __attribute__((ext_vector_type(8)));
typedef float f32x4 __attribute__((ext_vector_type(4)));

__device__ inline unsigned short f2h(float f) {
  _Float16 h = (_Float16)f;   // RNE
  return __builtin_bit_cast(unsigned short, h);
}

#define GLD_LDS16(gsrc, ldst)                                                        \
  __builtin_amdgcn_global_load_lds(                                                  \
      (const __attribute__((address_space(1))) unsigned int*)(gsrc),                 \
      (__attribute__((address_space(3))) unsigned int*)(ldst), 16, 0, 0)

// ---------------- fused: W transpose->fp16 (z=0,1) + Ad/Bd precompute (z=2) ----------------
__global__ void prep_k(const float* __restrict__ W1, const float* __restrict__ W2,
                       unsigned short* __restrict__ WT1, unsigned short* __restrict__ WT2,
                       const float* __restrict__ log_dt,
                       const float* __restrict__ log_A_real,
                       const float* __restrict__ A_imag,
                       const float* __restrict__ B_ri,
                       float4* __restrict__ AB,
                       float2* __restrict__ AP) {
  int tx = threadIdx.x;
  int ty = threadIdx.y;
  if (blockIdx.z == 2) {
    int flat = blockIdx.y * 16 + blockIdx.x;
    if (flat >= 64) return;
    int i = flat * 256 + ty * 32 + tx;
    int n = i & 31;
    int h = i >> 5;
    float dt = expf(log_dt[h]);
    float ar = -expf(log_A_real[i]);
    float ai = A_imag[i];
    float dr = 0.5f * dt * ar;
    float di = 0.5f * dt * ai;
    float omr = 1.0f - dr;
    float inv = 1.0f / (omr * omr + di * di);
    float adr = (1.0f - dr * dr - di * di) * inv;
    float adi = 2.0f * di * inv;
    float br = B_ri[2 * n];
    float bi = B_ri[2 * n + 1];
    float bdr = dt * (br * omr - bi * di) * inv;
    float bdi = dt * (br * di + bi * omr) * inv;
    AB[i] = make_float4(adr, adi, bdr, bdi);
    float pr = adr, pi = adi;
#pragma unroll
    for (int s = 0; s < 7; ++s) {   // Ad^(2^7) = Ad^128
      float qr = pr * pr - pi * pi;
      float qi = 2.0f * pr * pi;
      pr = qr; pi = qi;
    }
    AP[i] = make_float2(pr, pi);
    return;
  }
  __shared__ float tile[32][33];
  const float* W = blockIdx.z ? W2 : W1;
  unsigned short* WT = blockIdx.z ? WT2 : WT1;
  int k0 = blockIdx.x * 32;
  int j0 = blockIdx.y * 32;
#pragma unroll
  for (int i = 0; i < 32; i += 8)
    tile[ty + i][tx] = W[(size_t)(k0 + ty + i) * H_ + j0 + tx];
  __syncthreads();
#pragma unroll
  for (int i = 0; i < 32; i += 8)
    WT[(size_t)(j0 + ty + i) * H_ + k0 + tx] = f2h(tile[tx][ty + i]);
}

// ---------------- phase 1: local chunk scans (zero init), u staged from x via LDS ----------------
// block = (c, ht, b); 1024 threads; thread = (grp -> h, n).
__global__ __launch_bounds__(1024) void phase1_k(const float* __restrict__ x,
                                                 const float4* __restrict__ AB,
                                                 float2* __restrict__ xend) {
  __shared__ float ut[LC][36];
  int c = blockIdx.x;            // 0..14 (chunk 15's end state never used)
  int ht = blockIdx.y;
  int b = blockIdx.z;
  int tid = threadIdx.x;
  // stage [128 t][32 h] tile of x, coalesced
  {
    int r = tid >> 3;
    int q = tid & 7;
    float4 v = *(const float4*)(x + ((size_t)(b * L_ + c * LC + r) * H_) + ht * 32 + q * 4);
    *(float4*)&ut[r][q * 4] = v;
  }
  __syncthreads();
  int grp = tid >> 5;            // h index within tile
  int n = tid & 31;
  int h = ht * 32 + grp;
  int bh = b * H_ + h;
  float4 ab = AB[(h << 5) + n];
  float xr = 0.f, xi = 0.f;
#pragma unroll 8
  for (int t = 0; t < LC; ++t) {
    float uu = ut[t][grp];
    float nr = fmaf(ab.x, xr, fmaf(-ab.y, xi, ab.z * uu));
    float ni = fmaf(ab.y, xr, fmaf(ab.x, xi, ab.w * uu));
    xr = nr; xi = ni;
  }
  xend[((size_t)bh * NC + c) * 32 + n] = make_float2(xr, xi);
}

// ---------------- phase 2: propagate chunk-boundary states ----------------
__global__ void phase2_k(const float2* __restrict__ xend,
                         const float2* __restrict__ AP,
                         float2* __restrict__ xstart) {
  int tid = blockIdx.x * 256 + threadIdx.x;   // (b*H_+h)*32 + n
  int n = tid & 31;
  int bh = tid >> 5;
  int h = bh & (H_ - 1);
  float2 ap = AP[(h << 5) + n];
  float xr = 0.f, xi = 0.f;
  for (int c = 0; c < NC; ++c) {
    size_t idx = ((size_t)bh * NC + c) * 32 + n;
    xstart[idx] = make_float2(xr, xi);
    if (c < NC - 1) {
      float2 e = xend[idx];
      float nr = fmaf(ap.x, xr, fmaf(-ap.y, xi, e.x));
      float ni = fmaf(ap.y, xr, fmaf(ap.x, xi, e.y));
      xr = nr; xi = ni;
    }
  }
}

// ---------------- phase 3: 8-lane groups, 4 n per lane, v[8] butterfly ----------------
// block = (c, ht, b); 256 threads; group (8 lanes) <-> one h; lane owns n = ln*4..ln*4+3.
__global__ __launch_bounds__(256) void phase3_k(const float* __restrict__ x,
                                                const float4* __restrict__ AB,
                                                const float2* __restrict__ Cri,
                                                const float* __restrict__ Dv,
                                                const float2* __restrict__ xstart,
                                                unsigned short* __restrict__ yN) {
  __shared__ float ut[LC][36];
  __shared__ float ylds[2][8][36];
  int c = blockIdx.x;
  int ht = blockIdx.y;
  int b = blockIdx.z;
  int tid = threadIdx.x;
  // stage u tile [128 t][32 h]
#pragma unroll
  for (int i = 0; i < 4; ++i) {
    int r = i * 32 + (tid >> 3);
    int q = tid & 7;
    float4 v = *(const float4*)(x + ((size_t)(b * L_ + c * LC + r) * H_) + ht * 32 + q * 4);
    *(float4*)&ut[r][q * 4] = v;
  }
  int grp = tid >> 3;             // 0..31 -> h
  int ln = tid & 7;               // 0..7
  int h = ht * 32 + grp;
  int bh = b * H_ + h;

  float4 ab[4];
  float2 cc[4];
#pragma unroll
  for (int i = 0; i < 4; ++i) {
    ab[i] = AB[(h << 5) + ln * 4 + i];
    cc[i] = Cri[(h << 5) + ln * 4 + i];
  }
  float dd8 = Dv[h] * 0.125f;

  const float4* xs4 = (const float4*)(xstart + ((size_t)(bh * NC + c) * 32 + ln * 4));
  float4 s01 = xs4[0], s23 = xs4[1];
  float xr[4] = {s01.x, s01.z, s23.x, s23.z};
  float xi[4] = {s01.y, s01.w, s23.y, s23.w};
  __syncthreads();

#pragma unroll
  for (int w = 0; w < 16; ++w) {
    float v[8];
#define P3STEP(S)                                                            \
    {                                                                        \
      float uu = ut[w * 8 + (S)][grp];                                       \
      float acc = dd8 * uu;                                                  \
      _Pragma("unroll")                                                      \
      for (int i = 0; i < 4; ++i) {                                          \
        float nr = fmaf(ab[i].x, xr[i], fmaf(-ab[i].y, xi[i], ab[i].z * uu));\
        float ni = fmaf(ab[i].y, xr[i], fmaf(ab[i].x, xi[i], ab[i].w * uu)); \
        xr[i] = nr; xi[i] = ni;                                              \
        acc = fmaf(cc[i].x, nr, fmaf(-cc[i].y, ni, acc));                    \
      }                                                                      \
      v[(S)] = acc;                                                          \
    }
    P3STEP(0) P3STEP(1) P3STEP(2) P3STEP(3)
    P3STEP(4) P3STEP(5) P3STEP(6) P3STEP(7)
    // 3-stage reduce-scatter butterfly over 8 lanes; literal indices only.
#define BFLY(J, M)                                                           \
    {                                                                        \
      bool hi = (ln & (M)) != 0;                                             \
      float snd = hi ? v[(J)] : v[(J) + (M)];                                \
      float rcv = __shfl_xor(snd, (M));                                      \
      float kp = hi ? v[(J) + (M)] : v[(J)];                                 \
      v[(J)] = kp + rcv;                                                     \
    }
    BFLY(0, 4) BFLY(1, 4) BFLY(2, 4) BFLY(3, 4)
    BFLY(0, 2) BFLY(1, 2)
    BFLY(0, 1)
    // lane ln holds y[t0+ln] for this h
    ylds[w & 1][ln][grp] = v[0];
    __syncthreads();
    int t = tid >> 5;           // 0..7
    int hh = tid & 31;
    float val = ylds[w & 1][t][hh];
    yN[((size_t)b * L_ + c * LC + w * 8 + t) * H_ + ht * 32 + hh] = f2h(val);
    // no trailing sync: next window writes the other ylds buffer
  }
}

// ---------------- fused GLU GEMM (fp16 MFMA, double-buffered LDS) ----------------
// A = yN (M=8192, K=512) fp16 row-major; B = WT1/WT2 (N=512, K=512) fp16 row-major.
// BM=128, BN=64, BK=64; 4 waves, wave tile 64x32; T3-min: stage(next) || compute(cur).
__global__ __launch_bounds__(256) void glu_gemm_k(const unsigned short* __restrict__ yN,
                                                  const unsigned short* __restrict__ WT1,
                                                  const unsigned short* __restrict__ WT2,
                                                  float* __restrict__ out) {
  __shared__ __align__(16) char lds[65536];   // 2 x (A:16KB B1:8KB B2:8KB)
  int tid = threadIdx.x;
  int m0 = blockIdx.x * 128;
  int n0 = blockIdx.y * 64;
  int wave = tid >> 6;
  int lane = tid & 63;
  int wm = wave >> 1;
  int wn = wave & 1;
  int srow = tid >> 3;          // 0..31
  int scb = (tid & 7) * 16;     // col-bytes within 128B row

  f32x4 acc1[4][2], acc2[4][2];
#pragma unroll
  for (int mf = 0; mf < 4; ++mf)
#pragma unroll
    for (int nf = 0; nf < 2; ++nf) {
      f32x4 z; z[0] = 0.f; z[1] = 0.f; z[2] = 0.f; z[3] = 0.f;
      acc1[mf][nf] = z; acc2[mf][nf] = z;
    }

  const char* ybase = (const char*)yN;
  const char* b1base = (const char*)WT1;
  const char* b2base = (const char*)WT2;

#define STAGE(BUF, K0)                                                            \
  {                                                                               \
    char* As_ = lds + (BUF) * 32768;                                              \
    char* B1_ = As_ + 16384;                                                      \
    char* B2_ = As_ + 24576;                                                      \
    _Pragma("unroll")                                                             \
    for (int i = 0; i < 4; ++i) {                                                 \
      int row = i * 32 + srow;                                                    \
      int sc = scb ^ ((row & 7) << 4);                                            \
      GLD_LDS16(ybase + ((size_t)(m0 + row) * H_ + (K0)) * 2 + sc,                \
                As_ + wave * 1024 + i * 4096);                                    \
    }                                                                             \
    _Pragma("unroll")                                                             \
    for (int i = 0; i < 2; ++i) {                                                 \
      int row = i * 32 + srow;                                                    \
      int sc = scb ^ ((row & 7) << 4);                                            \
      GLD_LDS16(b1base + ((size_t)(n0 + row) * H_ + (K0)) * 2 + sc,               \
                B1_ + wave * 1024 + i * 4096);                                    \
      GLD_LDS16(b2base + ((size_t)(n0 + row) * H_ + (K0)) * 2 + sc,               \
                B2_ + wave * 1024 + i * 4096);                                    \
    }                                                                             \
  }

  STAGE(0, 0)
  __syncthreads();
  for (int k0 = 0; k0 < H_; k0 += 64) {
    int cur = (k0 >> 6) & 1;
    if (k0 + 64 < H_) STAGE(cur ^ 1, k0 + 64)
    const char* As = lds + cur * 32768;
    const char* B1s = As + 16384;
    const char* B2s = As + 24576;
#pragma unroll
    for (int ks = 0; ks < 2; ++ks) {
      f16x8 a[4], b1[2], b2[2];
      int kb = ks * 64 + (lane >> 4) * 16;
#pragma unroll
      for (int mf = 0; mf < 4; ++mf) {
        int row = wm * 64 + mf * 16 + (lane & 15);
        a[mf] = *(const f16x8*)(As + row * 128 + (kb ^ ((row & 7) << 4)));
      }
#pragma unroll
      for (int nf = 0; nf < 2; ++nf) {
        int row = wn * 32 + nf * 16 + (lane & 15);
        int off = row * 128 + (kb ^ ((row & 7) << 4));
        b1[nf] = *(const f16x8*)(B1s + off);
        b2[nf] = *(const f16x8*)(B2s + off);
      }
#pragma unroll
      for (int mf = 0; mf < 4; ++mf)
#pragma unroll
        for (int nf = 0; nf < 2; ++nf) {
          acc1[mf][nf] = __builtin_amdgcn_mfma_f32_16x16x32_f16(a[mf], b1[nf], acc1[mf][nf], 0, 0, 0);
          acc2[mf][nf] = __builtin_amdgcn_mfma_f32_16x16x32_f16(a[mf], b2[nf], acc2[mf][nf], 0, 0, 0);
        }
    }
    __syncthreads();   // drains prefetch (vmcnt) + protects buffer swap
  }
  // epilogue: o = g1 * sigmoid(g2); D layout col=lane&15, row=(lane>>4)*4+r
  int nb = n0 + wn * 32 + (lane & 15);
  int rbase = (lane >> 4) * 4;
#pragma unroll
  for (int mf = 0; mf < 4; ++mf)
#pragma unroll
    for (int nf = 0; nf < 2; ++nf)
#pragma unroll
      for (int r = 0; r < 4; ++r) {
        int m = m0 + wm * 64 + mf * 16 + rbase + r;
        float g1 = acc1[mf][nf][r];
        float g2 = acc2[mf][nf][r];
        out[(size_t)m * H_ + nb + nf * 16] = g1 / (1.0f + __expf(-g2));
      }
}

extern "C" void kernel_launch(void* const* d_in, const int* in_sizes, int n_in,
                              void* d_out, int out_size, void* d_ws, size_t ws_size,
                              hipStream_t stream) {
  (void)in_sizes; (void)n_in; (void)out_size; (void)ws_size;
  const float* x          = (const float*)d_in[0];
  const float* log_dt     = (const float*)d_in[1];
  const float* log_A_real = (const float*)d_in[2];
  const float* A_imag     = (const float*)d_in[3];
  const float* B_ri       = (const float*)d_in[4];
  const float* C_ri       = (const float*)d_in[5];
  const float* Dv         = (const float*)d_in[6];
  const float* W1         = (const float*)d_in[7];
  const float* W2         = (const float*)d_in[8];
  float* out = (float*)d_out;
  char* ws = (char*)d_ws;

  unsigned short* yN     = (unsigned short*)(ws);                       // 8 MiB
  float4*         AB     = (float4*)(ws + (8u << 20));                  // 256 KiB
  float2*         AP     = (float2*)(ws + (8u << 20) + (256u << 10));   // 128 KiB
  float2*         xend   = (float2*)(ws + (9u << 20));                  // 8 MiB
  float2*         xstart = (float2*)(ws + (17u << 20));                 // 8 MiB
  unsigned short* WT1    = (unsigned short*)(ws + (25u << 20));         // 512 KiB
  unsigned short* WT2    = (unsigned short*)(ws + (25u << 20) + (512u << 10));

  dim3 pgrid(16, 16, 3);
  dim3 pblock(32, 8);
  prep_k<<<pgrid, pblock, 0, stream>>>(W1, W2, WT1, WT2, log_dt, log_A_real, A_imag, B_ri, AB, AP);

  dim3 g1(NC - 1, 16, B_);
  phase1_k<<<g1, 1024, 0, stream>>>(x, AB, xend);

  phase2_k<<<(B_ * H_ * N_) / 256, 256, 0, stream>>>(xend, AP, xstart);

  dim3 g3(NC, 16, B_);
  phase3_k<<<g3, 256, 0, stream>>>(x, AB, (const float2*)C_ri, Dv, xstart, yN);

  dim3 ggrid((B_ * L_) / 128, H_ / 64);
  glu_gemm_k<<<ggrid, 256, 0, stream>>>(yN, WT1, WT2, out);
}

// Round 9
// 80.188 us; speedup vs baseline: 11.1721x; 1.0010x over previous
//
#include <hip/hip_runtime.h>

#define H_ 512
#define N_ 32
#define B_ 4
#define L_ 2048
#define LC 128
#define NC 16   // L_/LC

typedef _Float16 f16x8 __attribute__((ext_vector_type(8)));
typedef float f32x4 __attribute__((ext_vector_type(4)));

__device__ inline unsigned short f2h(float f) {
  _Float16 h = (_Float16)f;   // RNE
  return __builtin_bit_cast(unsigned short, h);
}

#define GLD_LDS16(gsrc, ldst)                                                        \
  __builtin_amdgcn_global_load_lds(                                                  \
      (const __attribute__((address_space(1))) unsigned int*)(gsrc),                 \
      (__attribute__((address_space(3))) unsigned int*)(ldst), 16, 0, 0)

// Inline per-thread discretization: lane ln owns n = ln*4..ln*4+3 of row h.
#define DISCRETIZE(h, ln, ab, cc)                                                    \
  {                                                                                  \
    float dtv = expf(log_dt[(h)]);                                                   \
    _Pragma("unroll")                                                                \
    for (int i = 0; i < 4; ++i) {                                                    \
      int n = (ln) * 4 + i;                                                          \
      int idx = ((h) << 5) + n;                                                      \
      float ar = -expf(log_A_real[idx]);                                             \
      float ai = A_imag[idx];                                                        \
      float dr = 0.5f * dtv * ar, di = 0.5f * dtv * ai;                              \
      float omr = 1.0f - dr;                                                         \
      float inv = 1.0f / (omr * omr + di * di);                                      \
      ab[i].x = (1.0f - dr * dr - di * di) * inv;                                    \
      ab[i].y = 2.0f * di * inv;                                                     \
      float br = B_ri[2 * n], bi = B_ri[2 * n + 1];                                  \
      ab[i].z = dtv * (br * omr - bi * di) * inv;                                    \
      ab[i].w = dtv * (br * di + bi * omr) * inv;                                    \
      cc[i] = ((const float2*)C_ri)[idx];                                            \
    }                                                                                \
  }

// ---------------- scan1: W-transpose prologue + zero-init local chunk scans ----------------
// grid (NC-1, 16, B_) x 256 thr. Block = (chunk c, h-tile ht, batch b).
__global__ __launch_bounds__(256) void scan1_k(
    const float* __restrict__ x,
    const float* __restrict__ log_dt,
    const float* __restrict__ log_A_real,
    const float* __restrict__ A_imag,
    const float* __restrict__ B_ri,
    const float* __restrict__ C_ri,
    const float* __restrict__ W1,
    const float* __restrict__ W2,
    unsigned short* __restrict__ WT1,
    unsigned short* __restrict__ WT2,
    float2* __restrict__ xend) {
  __shared__ float ut[LC][36];
  int c = blockIdx.x, ht = blockIdx.y, b = blockIdx.z;
  int tid = threadIdx.x;

  // ---- W transpose prologue: contiguous flat id over the 960-block grid ----
  int flat = (b * 16 + ht) * (NC - 1) + c;   // 0..959, contiguous
  if (flat < 512) {
    float(*tile)[33] = (float(*)[33]) & ut[0][0];   // 4224 B, fits in ut
    const float* W = (flat >> 8) ? W2 : W1;
    unsigned short* WT = (flat >> 8) ? WT2 : WT1;
    int rem = flat & 255;
    int k0 = (rem & 15) << 5, j0 = (rem >> 4) << 5;
    int tx = tid & 31, ty = tid >> 5;
#pragma unroll
    for (int i = 0; i < 32; i += 8)
      tile[ty + i][tx] = W[(size_t)(k0 + ty + i) * H_ + j0 + tx];
    __syncthreads();
#pragma unroll
    for (int i = 0; i < 32; i += 8)
      WT[(size_t)(j0 + ty + i) * H_ + k0 + tx] = f2h(tile[tx][ty + i]);
    __syncthreads();
  }

  // ---- stage u tile [128 t][32 h], coalesced ----
#pragma unroll
  for (int i = 0; i < 4; ++i) {
    int r = i * 32 + (tid >> 3);
    int q = tid & 7;
    float4 v = *(const float4*)(x + ((size_t)(b * L_ + c * LC + r) * H_) + ht * 32 + q * 4);
    *(float4*)&ut[r][q * 4] = v;
  }

  int grp = tid >> 3, ln = tid & 7;
  int h = ht * 32 + grp, bh = b * H_ + h;
  float4 ab[4];
  float2 cc[4];
  DISCRETIZE(h, ln, ab, cc)
  (void)cc;
  __syncthreads();   // ut ready

  // ---- state-only local scan ----
  float xr[4] = {0.f, 0.f, 0.f, 0.f}, xi[4] = {0.f, 0.f, 0.f, 0.f};
#pragma unroll 8
  for (int t = 0; t < LC; ++t) {
    float uu = ut[t][grp];
#pragma unroll
    for (int i = 0; i < 4; ++i) {
      float nr = fmaf(ab[i].x, xr[i], fmaf(-ab[i].y, xi[i], ab[i].z * uu));
      float ni = fmaf(ab[i].y, xr[i], fmaf(ab[i].x, xi[i], ab[i].w * uu));
      xr[i] = nr; xi[i] = ni;
    }
  }
  float2* dst = xend + ((size_t)bh * NC + c) * 32 + ln * 4;
  dst[0] = make_float2(xr[0], xi[0]);
  dst[1] = make_float2(xr[1], xi[1]);
  dst[2] = make_float2(xr[2], xi[2]);
  dst[3] = make_float2(xr[3], xi[3]);
}

// ---------------- scan2: Horner lookback + full scan + butterfly -> yN fp16 (B,L,H) ----------------
// grid (NC, 16, B_) x 256 thr. Kernel boundary = grid-wide sync on xend.
__global__ __launch_bounds__(256) void scan2_k(
    const float* __restrict__ x,
    const float* __restrict__ log_dt,
    const float* __restrict__ log_A_real,
    const float* __restrict__ A_imag,
    const float* __restrict__ B_ri,
    const float* __restrict__ C_ri,
    const float* __restrict__ Dv,
    const float2* __restrict__ xend,
    unsigned short* __restrict__ yN) {
  __shared__ float ut[LC][36];
  __shared__ float ylds[2][8][36];
  int c = blockIdx.x, ht = blockIdx.y, b = blockIdx.z;
  int tid = threadIdx.x;

  // ---- stage u tile [128 t][32 h] ----
#pragma unroll
  for (int i = 0; i < 4; ++i) {
    int r = i * 32 + (tid >> 3);
    int q = tid & 7;
    float4 v = *(const float4*)(x + ((size_t)(b * L_ + c * LC + r) * H_) + ht * 32 + q * 4);
    *(float4*)&ut[r][q * 4] = v;
  }

  int grp = tid >> 3, ln = tid & 7;
  int h = ht * 32 + grp, bh = b * H_ + h;
  float4 ab[4];
  float2 cc[4];
  DISCRETIZE(h, ln, ab, cc)
  float dd8 = Dv[h] * 0.125f;

  // ---- lookback: xstart = Horner over xend[c'<c] with Ad^128 ----
  float2 ap[4];
#pragma unroll
  for (int i = 0; i < 4; ++i) {
    float pr = ab[i].x, pi = ab[i].y;
#pragma unroll
    for (int s = 0; s < 7; ++s) {   // Ad^(2^7) = Ad^128
      float qr = pr * pr - pi * pi;
      float qi = 2.0f * pr * pi;
      pr = qr; pi = qi;
    }
    ap[i] = make_float2(pr, pi);
  }
  float xr[4] = {0.f, 0.f, 0.f, 0.f}, xi[4] = {0.f, 0.f, 0.f, 0.f};
  for (int cp = 0; cp < c; ++cp) {
    const float2* e = xend + ((size_t)bh * NC + cp) * 32 + ln * 4;
    float4 e01 = *(const float4*)e;
    float4 e23 = *(const float4*)(e + 2);
    float er[4] = {e01.x, e01.z, e23.x, e23.z};
    float ei[4] = {e01.y, e01.w, e23.y, e23.w};
#pragma unroll
    for (int i = 0; i < 4; ++i) {
      float nr = fmaf(ap[i].x, xr[i], fmaf(-ap[i].y, xi[i], er[i]));
      float ni = fmaf(ap[i].y, xr[i], fmaf(ap[i].x, xi[i], ei[i]));
      xr[i] = nr; xi[i] = ni;
    }
  }
  __syncthreads();   // ut ready

  // ---- full scan + C-projection + 8-lane reduce-scatter butterfly ----
#pragma unroll
  for (int w = 0; w < 16; ++w) {
    float v[8];
#define P3STEP(S)                                                            \
    {                                                                        \
      float uu = ut[w * 8 + (S)][grp];                                       \
      float acc = dd8 * uu;                                                  \
      _Pragma("unroll")                                                      \
      for (int i = 0; i < 4; ++i) {                                          \
        float nr = fmaf(ab[i].x, xr[i], fmaf(-ab[i].y, xi[i], ab[i].z * uu));\
        float ni = fmaf(ab[i].y, xr[i], fmaf(ab[i].x, xi[i], ab[i].w * uu)); \
        xr[i] = nr; xi[i] = ni;                                              \
        acc = fmaf(cc[i].x, nr, fmaf(-cc[i].y, ni, acc));                    \
      }                                                                      \
      v[(S)] = acc;                                                          \
    }
    P3STEP(0) P3STEP(1) P3STEP(2) P3STEP(3)
    P3STEP(4) P3STEP(5) P3STEP(6) P3STEP(7)
#define BFLY(J, M)                                                           \
    {                                                                        \
      bool hi = (ln & (M)) != 0;                                             \
      float snd = hi ? v[(J)] : v[(J) + (M)];                                \
      float rcv = __shfl_xor(snd, (M));                                      \
      float kp = hi ? v[(J) + (M)] : v[(J)];                                 \
      v[(J)] = kp + rcv;                                                     \
    }
    BFLY(0, 4) BFLY(1, 4) BFLY(2, 4) BFLY(3, 4)
    BFLY(0, 2) BFLY(1, 2)
    BFLY(0, 1)
    ylds[w & 1][ln][grp] = v[0];
    __syncthreads();
    int t = tid >> 5;
    int hh = tid & 31;
    float val = ylds[w & 1][t][hh];
    yN[((size_t)b * L_ + c * LC + w * 8 + t) * H_ + ht * 32 + hh] = f2h(val);
    // next window writes the other ylds buffer; no trailing sync needed
  }
}

// ---------------- fused GLU GEMM (fp16 MFMA, double-buffered LDS) ----------------
__global__ __launch_bounds__(256) void glu_gemm_k(const unsigned short* __restrict__ yN,
                                                  const unsigned short* __restrict__ WT1,
                                                  const unsigned short* __restrict__ WT2,
                                                  float* __restrict__ out) {
  __shared__ __align__(16) char lds[65536];   // 2 x (A:16KB B1:8KB B2:8KB)
  int tid = threadIdx.x;
  int m0 = blockIdx.x * 128;
  int n0 = blockIdx.y * 64;
  int wave = tid >> 6;
  int lane = tid & 63;
  int wm = wave >> 1;
  int wn = wave & 1;
  int srow = tid >> 3;          // 0..31
  int scb = (tid & 7) * 16;     // col-bytes within 128B row

  f32x4 acc1[4][2], acc2[4][2];
#pragma unroll
  for (int mf = 0; mf < 4; ++mf)
#pragma unroll
    for (int nf = 0; nf < 2; ++nf) {
      f32x4 z; z[0] = 0.f; z[1] = 0.f; z[2] = 0.f; z[3] = 0.f;
      acc1[mf][nf] = z; acc2[mf][nf] = z;
    }

  const char* ybase = (const char*)yN;
  const char* b1base = (const char*)WT1;
  const char* b2base = (const char*)WT2;

#define STAGE(BUF, K0)                                                            \
  {                                                                               \
    char* As_ = lds + (BUF) * 32768;                                              \
    char* B1_ = As_ + 16384;                                                      \
    char* B2_ = As_ + 24576;                                                      \
    _Pragma("unroll")                                                             \
    for (int i = 0; i < 4; ++i) {                                                 \
      int row = i * 32 + srow;                                                    \
      int sc = scb ^ ((row & 7) << 4);                                            \
      GLD_LDS16(ybase + ((size_t)(m0 + row) * H_ + (K0)) * 2 + sc,                \
                As_ + wave * 1024 + i * 4096);                                    \
    }                                                                             \
    _Pragma("unroll")                                                             \
    for (int i = 0; i < 2; ++i) {                                                 \
      int row = i * 32 + srow;                                                    \
      int sc = scb ^ ((row & 7) << 4);                                            \
      GLD_LDS16(b1base + ((size_t)(n0 + row) * H_ + (K0)) * 2 + sc,               \
                B1_ + wave * 1024 + i * 4096);                                    \
      GLD_LDS16(b2base + ((size_t)(n0 + row) * H_ + (K0)) * 2 + sc,               \
                B2_ + wave * 1024 + i * 4096);                                    \
    }                                                                             \
  }

  STAGE(0, 0)
  __syncthreads();
  for (int k0 = 0; k0 < H_; k0 += 64) {
    int cur = (k0 >> 6) & 1;
    if (k0 + 64 < H_) STAGE(cur ^ 1, k0 + 64)
    const char* As = lds + cur * 32768;
    const char* B1s = As + 16384;
    const char* B2s = As + 24576;
#pragma unroll
    for (int ks = 0; ks < 2; ++ks) {
      f16x8 a[4], b1[2], b2[2];
      int kb = ks * 64 + (lane >> 4) * 16;
#pragma unroll
      for (int mf = 0; mf < 4; ++mf) {
        int row = wm * 64 + mf * 16 + (lane & 15);
        a[mf] = *(const f16x8*)(As + row * 128 + (kb ^ ((row & 7) << 4)));
      }
#pragma unroll
      for (int nf = 0; nf < 2; ++nf) {
        int row = wn * 32 + nf * 16 + (lane & 15);
        int off = row * 128 + (kb ^ ((row & 7) << 4));
        b1[nf] = *(const f16x8*)(B1s + off);
        b2[nf] = *(const f16x8*)(B2s + off);
      }
#pragma unroll
      for (int mf = 0; mf < 4; ++mf)
#pragma unroll
        for (int nf = 0; nf < 2; ++nf) {
          acc1[mf][nf] = __builtin_amdgcn_mfma_f32_16x16x32_f16(a[mf], b1[nf], acc1[mf][nf], 0, 0, 0);
          acc2[mf][nf] = __builtin_amdgcn_mfma_f32_16x16x32_f16(a[mf], b2[nf], acc2[mf][nf], 0, 0, 0);
        }
    }
    __syncthreads();   // drains prefetch + protects buffer swap
  }
  int nb = n0 + wn * 32 + (lane & 15);
  int rbase = (lane >> 4) * 4;
#pragma unroll
  for (int mf = 0; mf < 4; ++mf)
#pragma unroll
    for (int nf = 0; nf < 2; ++nf)
#pragma unroll
      for (int r = 0; r < 4; ++r) {
        int m = m0 + wm * 64 + mf * 16 + rbase + r;
        float g1 = acc1[mf][nf][r];
        float g2 = acc2[mf][nf][r];
        out[(size_t)m * H_ + nb + nf * 16] = g1 / (1.0f + __expf(-g2));
      }
}

extern "C" void kernel_launch(void* const* d_in, const int* in_sizes, int n_in,
                              void* d_out, int out_size, void* d_ws, size_t ws_size,
                              hipStream_t stream) {
  (void)in_sizes; (void)n_in; (void)out_size; (void)ws_size;
  const float* x          = (const float*)d_in[0];
  const float* log_dt     = (const float*)d_in[1];
  const float* log_A_real = (const float*)d_in[2];
  const float* A_imag     = (const float*)d_in[3];
  const float* B_ri       = (const float*)d_in[4];
  const float* C_ri       = (const float*)d_in[5];
  const float* Dv         = (const float*)d_in[6];
  const float* W1         = (const float*)d_in[7];
  const float* W2         = (const float*)d_in[8];
  float* out = (float*)d_out;
  char* ws = (char*)d_ws;

  unsigned short* yN   = (unsigned short*)(ws);                       // 8 MiB
  float2*         xend = (float2*)(ws + (8u << 20));                  // 8 MiB
  unsigned short* WT1  = (unsigned short*)(ws + (16u << 20));         // 512 KiB
  unsigned short* WT2  = (unsigned short*)(ws + (16u << 20) + (512u << 10));

  scan1_k<<<dim3(NC - 1, 16, B_), 256, 0, stream>>>(
      x, log_dt, log_A_real, A_imag, B_ri, C_ri, W1, W2, WT1, WT2, xend);

  scan2_k<<<dim3(NC, 16, B_), 256, 0, stream>>>(
      x, log_dt, log_A_real, A_imag, B_ri, C_ri, Dv, xend, yN);

  dim3 ggrid((B_ * L_) / 128, H_ / 64);
  glu_gemm_k<<<ggrid, 256, 0, stream>>>(yN, WT1, WT2, out);
}